// Round 6
// baseline (409.240 us; speedup 1.0000x reference)
//
#include <hip/hip_runtime.h>
#include <math.h>

#define IN_DIM_C 128
#define OUT_DIM_C 64
#define T_STEPS 8
#define KC_MAX 512          // max coarse buckets (N/256 = 391 actual)
#define PTILE 2048          // edges per k_part block
#define GKC 32              // k-chunk for gemm staging
#define XSTR 260            // xs LDS stride (mult of 4 for b128 align; 260%32=4 -> 4-way wr)

__device__ __forceinline__ float4 f4zero() { return make_float4(0.f, 0.f, 0.f, 0.f); }

// ---------------- merged GEMM + coarse histogram ----------------------------------------
// Blocks [0, gemm_blocks): h = x @ W, 256-node tile, 8x8 thread tile (4 ds_read_b128 per
// 64 FMA vs 6/64 in the 128-tile version). a-reads conflict-free (8 distinct 32B-spaced
// addrs/wave at fixed k). FMA chain k=0..127 sequential per output => h bitwise identical.
// Blocks [gemm_blocks..): per-block LDS hist -> global chist (rides in gemm's shadow).
__global__ __launch_bounds__(256) void k_gemm_hist(const float* __restrict__ x,
                                                   const float* __restrict__ W,
                                                   float* __restrict__ h,
                                                   const int* __restrict__ dst,
                                                   int* __restrict__ chist,
                                                   int n, int E, int gemm_blocks) {
    __shared__ __align__(16) float smem[GKC * XSTR + GKC * OUT_DIM_C];  // 41.3 KB

    if ((int)blockIdx.x < gemm_blocks) {
        float* xs = smem;                  // [k][node], stride XSTR
        float* Ws = smem + GKC * XSTR;     // [k][col]
        const int tid = threadIdx.x;
        const int cg = tid & 7;            // col group: cols cg*8 .. +7
        const int ng = tid >> 3;           // node group: nodes ng*8 .. +7 (0..31)
        const int node_base = blockIdx.x * 256;

        float acc[8][8];
        #pragma unroll
        for (int i = 0; i < 8; ++i)
            #pragma unroll
            for (int j = 0; j < 8; ++j) acc[i][j] = 0.f;

        #pragma unroll 1
        for (int c = 0; c < IN_DIM_C / GKC; ++c) {
            __syncthreads();
            // stage x chunk transposed: 256 nodes x 32 k (8 float4 loads/thread, coalesced)
            #pragma unroll
            for (int i = 0; i < 8; ++i) {
                int idx = tid + i * 256;          // 0..2047
                int nd = idx >> 3, k4 = idx & 7;
                int node = node_base + nd;
                float4 v = f4zero();
                if (node < n) v = *(const float4*)&x[(long)node * IN_DIM_C + c * GKC + k4 * 4];
                xs[(k4 * 4 + 0) * XSTR + nd] = v.x;
                xs[(k4 * 4 + 1) * XSTR + nd] = v.y;
                xs[(k4 * 4 + 2) * XSTR + nd] = v.z;
                xs[(k4 * 4 + 3) * XSTR + nd] = v.w;
            }
            // stage W chunk: 32 rows x 64 cols, contiguous
            #pragma unroll
            for (int i = 0; i < 2; ++i) {
                int idx = tid + i * 256;
                ((float4*)Ws)[idx] = ((const float4*)&W[c * GKC * OUT_DIM_C])[idx];
            }
            __syncthreads();

            #pragma unroll 4
            for (int k = 0; k < GKC; ++k) {
                float4 a0 = *(const float4*)&xs[k * XSTR + ng * 8];
                float4 a1 = *(const float4*)&xs[k * XSTR + ng * 8 + 4];
                const float* wr = &Ws[k * OUT_DIM_C + cg * 8];
                float4 b0 = *(const float4*)&wr[0];
                float4 b1 = *(const float4*)&wr[4];
                #pragma unroll
                for (int i = 0; i < 8; ++i) {
                    float av = (i == 0) ? a0.x : (i == 1) ? a0.y : (i == 2) ? a0.z
                             : (i == 3) ? a0.w : (i == 4) ? a1.x : (i == 5) ? a1.y
                             : (i == 6) ? a1.z : a1.w;
                    acc[i][0] = fmaf(av, b0.x, acc[i][0]);
                    acc[i][1] = fmaf(av, b0.y, acc[i][1]);
                    acc[i][2] = fmaf(av, b0.z, acc[i][2]);
                    acc[i][3] = fmaf(av, b0.w, acc[i][3]);
                    acc[i][4] = fmaf(av, b1.x, acc[i][4]);
                    acc[i][5] = fmaf(av, b1.y, acc[i][5]);
                    acc[i][6] = fmaf(av, b1.z, acc[i][6]);
                    acc[i][7] = fmaf(av, b1.w, acc[i][7]);
                }
            }
        }

        #pragma unroll
        for (int i = 0; i < 8; ++i) {
            int node = node_base + ng * 8 + i;
            if (node < n) {
                *(float4*)&h[(long)node * OUT_DIM_C + cg * 8] =
                    make_float4(acc[i][0], acc[i][1], acc[i][2], acc[i][3]);
                *(float4*)&h[(long)node * OUT_DIM_C + cg * 8 + 4] =
                    make_float4(acc[i][4], acc[i][5], acc[i][6], acc[i][7]);
            }
        }
    } else {
        int* hh = (int*)smem;
        const int tid = threadIdx.x;
        int hb = blockIdx.x - gemm_blocks;
        for (int i = tid; i < KC_MAX; i += 256) hh[i] = 0;
        __syncthreads();
        long base = (long)hb * 4096;
        #pragma unroll
        for (int j = 0; j < 16; ++j) {
            long e = base + j * 256 + tid;
            if (e < E) atomicAdd(&hh[dst[e] >> 8], 1);
        }
        __syncthreads();
        for (int i = tid; i < KC_MAX; i += 256)
            if (hh[i]) atomicAdd(&chist[i], hh[i]);
    }
}

// ---------------- coarse partition (self-contained: scans chist in-block) ----------------
// gcursor is ZERO-initialized; each block computes the global bucket prefix from chist
// (wave-0 dual scan: local hist + global chist) -> no separate k_scanK kernel/bubble.
// packed = (src << 8) | (dst & 255); only 391 concurrent write windows -> L2 combines.
__global__ __launch_bounds__(256) void k_part(const int* __restrict__ src,
                                              const int* __restrict__ dst,
                                              const int* __restrict__ chist,
                                              int* __restrict__ gcursor,
                                              int* __restrict__ part, int E, int kc) {
    __shared__ int hist[KC_MAX];
    __shared__ int offs[KC_MAX];
    __shared__ int cur[KC_MAX];
    __shared__ int gbase[KC_MAX];
    __shared__ int pref[KC_MAX];
    const int tid = threadIdx.x;
    long base = (long)blockIdx.x * PTILE;

    for (int i = tid; i < KC_MAX; i += 256) hist[i] = 0;
    __syncthreads();
    #pragma unroll
    for (int j = 0; j < PTILE / 256; ++j) {
        long e = base + j * 256 + tid;
        if (e < E) atomicAdd(&hist[dst[e] >> 8], 1);
    }
    __syncthreads();
    // wave 0: exclusive scan of local hist AND global chist
    if (tid < 64) {
        int carry = 0, carryG = 0;
        for (int c = 0; c * 64 < kc; ++c) {
            int idx = c * 64 + tid;
            int v  = (idx < kc) ? hist[idx] : 0;
            int vg = (idx < kc) ? chist[idx] : 0;
            int x = v, xg = vg;
            #pragma unroll
            for (int off = 1; off < 64; off <<= 1) {
                int t  = __shfl_up(x, off, 64);
                int tg = __shfl_up(xg, off, 64);
                if (tid >= off) { x += t; xg += tg; }
            }
            if (idx < kc) {
                offs[idx] = carry + x - v;
                cur[idx]  = carry + x - v;
                pref[idx] = carryG + xg - vg;
            }
            carry  += __shfl(x, 63, 64);
            carryG += __shfl(xg, 63, 64);
        }
    }
    __syncthreads();
    for (int b = tid; b < kc; b += 256)
        gbase[b] = hist[b] ? pref[b] + atomicAdd(&gcursor[b], hist[b]) : 0;
    __syncthreads();
    #pragma unroll
    for (int j = 0; j < PTILE / 256; ++j) {
        long e = base + j * 256 + tid;
        if (e < E) {
            int d = dst[e];
            int b = d >> 8;
            int r = atomicAdd(&cur[b], 1);
            part[gbase[b] + r - offs[b]] = (src[e] << 8) | (d & 255);
        }
    }
}

// ---------------- fine sort within bucket (self-contained start/end from chist) ----------
// start(b) = sum chist[0..b-1] via block reduce; also emits CSR offsets, dinv, offsets[n].
__global__ __launch_bounds__(256) void k_sort(const int* __restrict__ part,
                                              const int* __restrict__ chist,
                                              int* __restrict__ part2,
                                              int* __restrict__ offsets,
                                              float* __restrict__ dinv,
                                              int n, int E, int kc) {
    __shared__ int cnt[256];
    __shared__ int cur[256];
    __shared__ int wsum[4], woff[4];
    __shared__ int sred[4];
    __shared__ int sstart;
    const int tid = threadIdx.x;
    const int bkt = blockIdx.x;

    // block reduce: start = sum of chist[i < bkt]
    int s = 0;
    for (int i = tid; i < bkt; i += 256) s += chist[i];
    #pragma unroll
    for (int m = 1; m < 64; m <<= 1) s += __shfl_xor(s, m, 64);
    if ((tid & 63) == 0) sred[tid >> 6] = s;
    cnt[tid] = 0;
    __syncthreads();
    if (tid == 0) sstart = sred[0] + sred[1] + sred[2] + sred[3];
    __syncthreads();
    const int start = sstart;
    const int end = start + chist[bkt];

    for (int i = start + tid; i < end; i += 256)
        atomicAdd(&cnt[part[i] & 255], 1);
    __syncthreads();

    int v = cnt[tid];
    int lane = tid & 63, wv = tid >> 6;
    int x = v;
    #pragma unroll
    for (int off = 1; off < 64; off <<= 1) {
        int t = __shfl_up(x, off, 64);
        if (lane >= off) x += t;
    }
    if (lane == 63) wsum[wv] = x;
    __syncthreads();
    if (tid == 0) { int c = 0; for (int w = 0; w < 4; ++w) { woff[w] = c; c += wsum[w]; } }
    __syncthreads();
    int myloc = woff[wv] + x - v;            // exclusive local offset
    cur[tid] = myloc;
    int node = (bkt << 8) + tid;
    if (node < n) {
        offsets[node] = start + myloc;
        dinv[node] = rsqrtf((float)(v + 1));
    }
    if (bkt == kc - 1 && tid == 0) offsets[n] = E;
    __syncthreads();

    for (int i = start + tid; i < end; i += 256) {
        int p = part[i];
        int r = atomicAdd(&cur[p & 255], 1);
        part2[start + r] = ((unsigned)p) >> 8;   // src node id
    }
}

// ---------------- fused pull+spike: 16 lanes/node, 8-deep gather unroll ------------------
__global__ __launch_bounds__(256) void k_pullspike(const int* __restrict__ offsets,
                                                   const int* __restrict__ part2,
                                                   const float* __restrict__ dinv,
                                                   const float* __restrict__ h,
                                                   const float* __restrict__ b,
                                                   float* __restrict__ o_seq,
                                                   float* __restrict__ z_seq, int n) {
    int gid = blockIdx.x * 256 + threadIdx.x;
    int node = gid >> 4;
    int sub = threadIdx.x & 15;
    if (node >= n) return;
    const float s0 = (sub == 0) ? -1.0f : 1.0f;
    int lane0 = (threadIdx.x & 63) & ~15;

    // ---- pull phase ----
    int o0 = offsets[node], o1 = offsets[node + 1];
    float dd = dinv[node];
    float4 hv = *(const float4*)&h[(long)node * OUT_DIM_C + sub * 4];
    float4 bv = *(const float4*)&b[sub * 4];
    float dd2 = dd * dd;
    float4 g = make_float4(fmaf(dd2, hv.x, bv.x), fmaf(dd2, hv.y, bv.y),
                           fmaf(dd2, hv.z, bv.z), fmaf(dd2, hv.w, bv.w));
    int i = o0;
    for (; i + 8 <= o1; i += 8) {
        int sa0 = part2[i],     sa1 = part2[i + 1], sa2 = part2[i + 2], sa3 = part2[i + 3];
        int sa4 = part2[i + 4], sa5 = part2[i + 5], sa6 = part2[i + 6], sa7 = part2[i + 7];
        float w0 = dinv[sa0] * dd, w1 = dinv[sa1] * dd, w2 = dinv[sa2] * dd, w3 = dinv[sa3] * dd;
        float w4 = dinv[sa4] * dd, w5 = dinv[sa5] * dd, w6 = dinv[sa6] * dd, w7 = dinv[sa7] * dd;
        float4 h0 = *(const float4*)&h[(long)sa0 * OUT_DIM_C + sub * 4];
        float4 h1 = *(const float4*)&h[(long)sa1 * OUT_DIM_C + sub * 4];
        float4 h2 = *(const float4*)&h[(long)sa2 * OUT_DIM_C + sub * 4];
        float4 h3 = *(const float4*)&h[(long)sa3 * OUT_DIM_C + sub * 4];
        float4 h4 = *(const float4*)&h[(long)sa4 * OUT_DIM_C + sub * 4];
        float4 h5 = *(const float4*)&h[(long)sa5 * OUT_DIM_C + sub * 4];
        float4 h6 = *(const float4*)&h[(long)sa6 * OUT_DIM_C + sub * 4];
        float4 h7 = *(const float4*)&h[(long)sa7 * OUT_DIM_C + sub * 4];
        g.x = fmaf(w0, h0.x, g.x); g.y = fmaf(w0, h0.y, g.y);
        g.z = fmaf(w0, h0.z, g.z); g.w = fmaf(w0, h0.w, g.w);
        g.x = fmaf(w1, h1.x, g.x); g.y = fmaf(w1, h1.y, g.y);
        g.z = fmaf(w1, h1.z, g.z); g.w = fmaf(w1, h1.w, g.w);
        g.x = fmaf(w2, h2.x, g.x); g.y = fmaf(w2, h2.y, g.y);
        g.z = fmaf(w2, h2.z, g.z); g.w = fmaf(w2, h2.w, g.w);
        g.x = fmaf(w3, h3.x, g.x); g.y = fmaf(w3, h3.y, g.y);
        g.z = fmaf(w3, h3.z, g.z); g.w = fmaf(w3, h3.w, g.w);
        g.x = fmaf(w4, h4.x, g.x); g.y = fmaf(w4, h4.y, g.y);
        g.z = fmaf(w4, h4.z, g.z); g.w = fmaf(w4, h4.w, g.w);
        g.x = fmaf(w5, h5.x, g.x); g.y = fmaf(w5, h5.y, g.y);
        g.z = fmaf(w5, h5.z, g.z); g.w = fmaf(w5, h5.w, g.w);
        g.x = fmaf(w6, h6.x, g.x); g.y = fmaf(w6, h6.y, g.y);
        g.z = fmaf(w6, h6.z, g.z); g.w = fmaf(w6, h6.w, g.w);
        g.x = fmaf(w7, h7.x, g.x); g.y = fmaf(w7, h7.y, g.y);
        g.z = fmaf(w7, h7.z, g.z); g.w = fmaf(w7, h7.w, g.w);
    }
    for (; i + 4 <= o1; i += 4) {
        int sa0 = part2[i], sa1 = part2[i + 1], sa2 = part2[i + 2], sa3 = part2[i + 3];
        float w0 = dinv[sa0] * dd, w1 = dinv[sa1] * dd;
        float w2 = dinv[sa2] * dd, w3 = dinv[sa3] * dd;
        float4 h0 = *(const float4*)&h[(long)sa0 * OUT_DIM_C + sub * 4];
        float4 h1 = *(const float4*)&h[(long)sa1 * OUT_DIM_C + sub * 4];
        float4 h2 = *(const float4*)&h[(long)sa2 * OUT_DIM_C + sub * 4];
        float4 h3 = *(const float4*)&h[(long)sa3 * OUT_DIM_C + sub * 4];
        g.x = fmaf(w0, h0.x, g.x); g.y = fmaf(w0, h0.y, g.y);
        g.z = fmaf(w0, h0.z, g.z); g.w = fmaf(w0, h0.w, g.w);
        g.x = fmaf(w1, h1.x, g.x); g.y = fmaf(w1, h1.y, g.y);
        g.z = fmaf(w1, h1.z, g.z); g.w = fmaf(w1, h1.w, g.w);
        g.x = fmaf(w2, h2.x, g.x); g.y = fmaf(w2, h2.y, g.y);
        g.z = fmaf(w2, h2.z, g.z); g.w = fmaf(w2, h2.w, g.w);
        g.x = fmaf(w3, h3.x, g.x); g.y = fmaf(w3, h3.y, g.y);
        g.z = fmaf(w3, h3.z, g.z); g.w = fmaf(w3, h3.w, g.w);
    }
    for (; i < o1; ++i) {
        int sidx = part2[i];
        float w = dinv[sidx] * dd;
        float4 h0 = *(const float4*)&h[(long)sidx * OUT_DIM_C + sub * 4];
        g.x = fmaf(w, h0.x, g.x); g.y = fmaf(w, h0.y, g.y);
        g.z = fmaf(w, h0.z, g.z); g.w = fmaf(w, h0.w, g.w);
    }

    // ---- spike phase ----
    float4 origin = f4zero();
    if (sub == 0) origin.x = 1.0f;

    auto step = [&](float4 z, float4& zn, bool& sp) {
        float p = s0 * z.x * g.x + z.y * g.y + z.z * g.z + z.w * g.w;
        p += __shfl_xor(p, 1, 64);
        p += __shfl_xor(p, 2, 64);
        p += __shfl_xor(p, 4, 64);
        p += __shfl_xor(p, 8, 64);
        float4 u = make_float4(fmaf(p, z.x, g.x), fmaf(p, z.y, g.y),
                               fmaf(p, z.z, g.z), fmaf(p, z.w, g.w));
        float q = s0 * u.x * u.x + u.y * u.y + u.z * u.z + u.w * u.w;
        q += __shfl_xor(q, 1, 64);
        q += __shfl_xor(q, 2, 64);
        q += __shfl_xor(q, 4, 64);
        q += __shfl_xor(q, 8, 64);
        float un = sqrtf(fmaxf(q, 1e-7f));
        float c = coshf(un);
        float sh = sinhf(un) / un;
        zn = make_float4(fmaf(c, z.x, sh * u.x), fmaf(c, z.y, sh * u.y),
                         fmaf(c, z.z, sh * u.z), fmaf(c, z.w, sh * u.w));
        float z0 = __shfl(zn.x, lane0, 64);
        float v = acoshf(fmaxf(z0, 1.0f + 1e-7f));
        sp = (v >= 1.0f);
    };

    float4 z1; bool sp0;
    step(origin, z1, sp0);
    float4 r0 = sp0 ? origin : z1;

    float4 z = origin;
    bool at0 = true;
    for (int t = 0; t < T_STEPS; ++t) {
        float4 zn; bool sp;
        if (at0) { sp = sp0; zn = r0; }
        else {
            step(z, zn, sp);
            if (sp) zn = origin;
        }
        *(float4*)&z_seq[(long)t * n * OUT_DIM_C + (long)node * OUT_DIM_C + sub * 4] = zn;
        if (sub == 0) o_seq[(long)t * n + node] = sp ? 1.0f : 0.0f;
        z = zn;
        at0 = sp;
    }
}

// ================= fallback split kernels (used when ws_size too small) ==================
__global__ __launch_bounds__(256) void k_hist(const int* __restrict__ dst,
                                              int* __restrict__ chist, int E) {
    __shared__ int hh[KC_MAX];
    const int tid = threadIdx.x;
    for (int i = tid; i < KC_MAX; i += 256) hh[i] = 0;
    __syncthreads();
    long base = (long)blockIdx.x * 4096;
    #pragma unroll
    for (int j = 0; j < 16; ++j) {
        long e = base + j * 256 + tid;
        if (e < E) atomicAdd(&hh[dst[e] >> 8], 1);
    }
    __syncthreads();
    for (int i = tid; i < KC_MAX; i += 256)
        if (hh[i]) atomicAdd(&chist[i], hh[i]);
}

__global__ __launch_bounds__(256) void k_gemm(const float* __restrict__ x,
                                              const float* __restrict__ W,
                                              float* __restrict__ h, int n) {
    __shared__ __align__(16) float xs[GKC * 132];
    __shared__ __align__(16) float Ws[GKC * OUT_DIM_C];

    const int tid = threadIdx.x;
    const int cg = tid & 7;
    const int ng = tid >> 3;
    const int node_base = blockIdx.x * 128;

    float acc[4][8];
    #pragma unroll
    for (int i = 0; i < 4; ++i)
        #pragma unroll
        for (int j = 0; j < 8; ++j) acc[i][j] = 0.f;

    #pragma unroll 1
    for (int c = 0; c < IN_DIM_C / GKC; ++c) {
        __syncthreads();
        #pragma unroll
        for (int i = 0; i < 4; ++i) {
            int idx = tid + i * 256;
            int nd = idx >> 3, k4 = idx & 7;
            int node = node_base + nd;
            float4 v = f4zero();
            if (node < n) v = *(const float4*)&x[(long)node * IN_DIM_C + c * GKC + k4 * 4];
            xs[(k4 * 4 + 0) * 132 + nd] = v.x;
            xs[(k4 * 4 + 1) * 132 + nd] = v.y;
            xs[(k4 * 4 + 2) * 132 + nd] = v.z;
            xs[(k4 * 4 + 3) * 132 + nd] = v.w;
        }
        #pragma unroll
        for (int i = 0; i < 2; ++i) {
            int idx = tid + i * 256;
            ((float4*)Ws)[idx] = ((const float4*)&W[c * GKC * OUT_DIM_C])[idx];
        }
        __syncthreads();

        #pragma unroll
        for (int k = 0; k < GKC; ++k) {
            float4 a = *(const float4*)&xs[k * 132 + ng * 4];
            const float* wr = &Ws[k * OUT_DIM_C + cg * 8];
            float4 b0 = *(const float4*)&wr[0];
            float4 b1 = *(const float4*)&wr[4];
            #pragma unroll
            for (int i = 0; i < 4; ++i) {
                float av = (i == 0) ? a.x : (i == 1) ? a.y : (i == 2) ? a.z : a.w;
                acc[i][0] = fmaf(av, b0.x, acc[i][0]);
                acc[i][1] = fmaf(av, b0.y, acc[i][1]);
                acc[i][2] = fmaf(av, b0.z, acc[i][2]);
                acc[i][3] = fmaf(av, b0.w, acc[i][3]);
                acc[i][4] = fmaf(av, b1.x, acc[i][4]);
                acc[i][5] = fmaf(av, b1.y, acc[i][5]);
                acc[i][6] = fmaf(av, b1.z, acc[i][6]);
                acc[i][7] = fmaf(av, b1.w, acc[i][7]);
            }
        }
    }

    #pragma unroll
    for (int i = 0; i < 4; ++i) {
        int node = node_base + ng * 4 + i;
        if (node < n) {
            *(float4*)&h[(long)node * OUT_DIM_C + cg * 8] =
                make_float4(acc[i][0], acc[i][1], acc[i][2], acc[i][3]);
            *(float4*)&h[(long)node * OUT_DIM_C + cg * 8 + 4] =
                make_float4(acc[i][4], acc[i][5], acc[i][6], acc[i][7]);
        }
    }
}

__global__ __launch_bounds__(256) void k_pull(const int* __restrict__ offsets,
                                              const int* __restrict__ part2,
                                              const float* __restrict__ dinv,
                                              const float* __restrict__ h,
                                              const float* __restrict__ b,
                                              float* __restrict__ agg, int n) {
    int node = (blockIdx.x * 256 + threadIdx.x) >> 6;
    int lane = threadIdx.x & 63;
    if (node >= n) return;
    int o0 = offsets[node], o1 = offsets[node + 1];
    float dd = dinv[node];
    float acc = fmaf(dd * dd, h[(long)node * OUT_DIM_C + lane], b[lane]);
    int i = o0;
    for (; i + 4 <= o1; i += 4) {
        int s0 = part2[i], s1 = part2[i + 1], s2 = part2[i + 2], s3 = part2[i + 3];
        float n0 = dinv[s0] * dd, n1 = dinv[s1] * dd, n2 = dinv[s2] * dd, n3 = dinv[s3] * dd;
        acc = fmaf(n0, h[(long)s0 * OUT_DIM_C + lane], acc);
        acc = fmaf(n1, h[(long)s1 * OUT_DIM_C + lane], acc);
        acc = fmaf(n2, h[(long)s2 * OUT_DIM_C + lane], acc);
        acc = fmaf(n3, h[(long)s3 * OUT_DIM_C + lane], acc);
    }
    for (; i < o1; ++i) {
        int s = part2[i];
        acc = fmaf(dinv[s] * dd, h[(long)s * OUT_DIM_C + lane], acc);
    }
    agg[(long)node * OUT_DIM_C + lane] = acc;
}

__global__ __launch_bounds__(256) void k_spike(const float* agg,
                                               float* o_seq, float* z_seq, int n) {
    int gid = blockIdx.x * 256 + threadIdx.x;
    int node = gid >> 4;
    int sub = threadIdx.x & 15;
    if (node >= n) return;
    const float s0 = (sub == 0) ? -1.0f : 1.0f;
    int lane0 = (threadIdx.x & 63) & ~15;

    float4 g = *(const float4*)&agg[(long)node * OUT_DIM_C + sub * 4];
    float4 origin = f4zero();
    if (sub == 0) origin.x = 1.0f;

    auto step = [&](float4 z, float4& zn, bool& sp) {
        float p = s0 * z.x * g.x + z.y * g.y + z.z * g.z + z.w * g.w;
        p += __shfl_xor(p, 1, 64);
        p += __shfl_xor(p, 2, 64);
        p += __shfl_xor(p, 4, 64);
        p += __shfl_xor(p, 8, 64);
        float4 u = make_float4(fmaf(p, z.x, g.x), fmaf(p, z.y, g.y),
                               fmaf(p, z.z, g.z), fmaf(p, z.w, g.w));
        float q = s0 * u.x * u.x + u.y * u.y + u.z * u.z + u.w * u.w;
        q += __shfl_xor(q, 1, 64);
        q += __shfl_xor(q, 2, 64);
        q += __shfl_xor(q, 4, 64);
        q += __shfl_xor(q, 8, 64);
        float un = sqrtf(fmaxf(q, 1e-7f));
        float c = coshf(un);
        float sh = sinhf(un) / un;
        zn = make_float4(fmaf(c, z.x, sh * u.x), fmaf(c, z.y, sh * u.y),
                         fmaf(c, z.z, sh * u.z), fmaf(c, z.w, sh * u.w));
        float z0 = __shfl(zn.x, lane0, 64);
        float v = acoshf(fmaxf(z0, 1.0f + 1e-7f));
        sp = (v >= 1.0f);
    };

    float4 z1; bool sp0;
    step(origin, z1, sp0);
    float4 r0 = sp0 ? origin : z1;

    float4 z = origin;
    bool at0 = true;
    for (int t = 0; t < T_STEPS; ++t) {
        float4 zn; bool sp;
        if (at0) { sp = sp0; zn = r0; }
        else {
            step(z, zn, sp);
            if (sp) zn = origin;
        }
        *(float4*)&z_seq[(long)t * n * OUT_DIM_C + (long)node * OUT_DIM_C + sub * 4] = zn;
        if (sub == 0) o_seq[(long)t * n + node] = sp ? 1.0f : 0.0f;
        z = zn;
        at0 = sp;
    }
}

static inline size_t align256(size_t x) { return (x + 255) & ~(size_t)255; }

extern "C" void kernel_launch(void* const* d_in, const int* in_sizes, int n_in,
                              void* d_out, int out_size, void* d_ws, size_t ws_size,
                              hipStream_t stream) {
    const float* x  = (const float*)d_in[0];
    const int*   ei = (const int*)d_in[1];
    const float* W  = (const float*)d_in[2];
    const float* b  = (const float*)d_in[3];
    const int N = in_sizes[0] / IN_DIM_C;   // 100000
    const int E = in_sizes[1] / 2;          // 1600000
    const int KC = (N + 255) >> 8;          // 391 coarse buckets

    float* out   = (float*)d_out;
    float* o_seq = out;                              // [T, N]
    float* z_seq = out + (long)T_STEPS * N;          // [T, N, 64]

    const int* srcp = ei;
    const int* dstp = ei + E;

    // ws layout (fused path): h | part2 | offsets | dinv  (~32.8 MB)
    size_t off_h    = 0;
    size_t off_p2   = align256(off_h + (size_t)N * OUT_DIM_C * 4);
    size_t off_offs = align256(off_p2 + (size_t)E * 4);
    size_t off_dinv = align256(off_offs + (size_t)(N + 1) * 4);
    size_t need     = align256(off_dinv + (size_t)N * 4);

    const int GB = (N + 255) / 256;         // gemm blocks (391)
    const int HB = (E + 4095) / 4096;       // hist blocks (391)

    if (d_ws != nullptr && ws_size >= need) {
        // ---- fused path: pull inputs live in ws, z_seq only written by k_pullspike ----
        float* h       = (float*)((char*)d_ws + off_h);
        int*   part2   = (int*)((char*)d_ws + off_p2);
        int*   offsets = (int*)((char*)d_ws + off_offs);
        float* dinv    = (float*)((char*)d_ws + off_dinv);
        // consumed-before-pullspike scratch aliases z_seq slabs:
        int*   part    = (int*)(z_seq + 0L * N * OUT_DIM_C);      // slab 0: E ints
        int*   chist   = (int*)(z_seq + 1L * N * OUT_DIM_C);      // slab 1: KC ints
        int*   gcursor = chist + KC_MAX;                          // KC ints (zeroed)

        hipMemsetAsync(chist, 0, (size_t)2 * KC_MAX * sizeof(int), stream);
        k_gemm_hist<<<GB + HB, 256, 0, stream>>>(x, W, h, dstp, chist, N, E, GB);
        k_part<<<(E + PTILE - 1) / PTILE, 256, 0, stream>>>(srcp, dstp, chist, gcursor,
                                                            part, E, KC);
        k_sort<<<KC, 256, 0, stream>>>(part, chist, part2, offsets, dinv, N, E, KC);
        k_pullspike<<<(N + 15) / 16, 256, 0, stream>>>(offsets, part2, dinv, h, b,
                                                       o_seq, z_seq, N);
    } else {
        // ---- fallback: split kernels, scratch aliased into z_seq slabs ----
        float* agg     = z_seq;                                   // slab 0
        float* h       = z_seq + 1L * N * OUT_DIM_C;              // slab 1
        int*   part    = (int*)(z_seq + 2L * N * OUT_DIM_C);      // slab 2: E ints
        int*   part2   = (int*)(z_seq + 3L * N * OUT_DIM_C);      // slab 3: E ints
        int*   chist   = (int*)(z_seq + 4L * N * OUT_DIM_C);      // slab 4: KC ints
        int*   gcursor = chist + KC_MAX;
        int*   offsets = gcursor + KC_MAX;
        float* dinv    = (float*)(offsets + N + 1);

        hipMemsetAsync(chist, 0, (size_t)2 * KC_MAX * sizeof(int), stream);
        k_hist<<<HB, 256, 0, stream>>>(dstp, chist, E);
        k_gemm<<<(N + 127) / 128, 256, 0, stream>>>(x, W, h, N);
        k_part<<<(E + PTILE - 1) / PTILE, 256, 0, stream>>>(srcp, dstp, chist, gcursor,
                                                            part, E, KC);
        k_sort<<<KC, 256, 0, stream>>>(part, chist, part2, offsets, dinv, N, E, KC);
        k_pull<<<(N * 64 + 255) / 256, 256, 0, stream>>>(offsets, part2, dinv, h, b, agg, N);
        k_spike<<<(N + 15) / 16, 256, 0, stream>>>(agg, o_seq, z_seq, N);
    }
}

// Round 7
// 380.282 us; speedup vs baseline: 1.0761x; 1.0761x over previous
//
#include <hip/hip_runtime.h>
#include <math.h>

#define IN_DIM_C 128
#define OUT_DIM_C 64
#define T_STEPS 8
#define KC_MAX 512          // max coarse buckets (N/256 = 391 actual)
#define PTILE 2048          // edges per k_part block
#define GKC 32              // k-chunk for gemm staging

__device__ __forceinline__ float4 f4zero() { return make_float4(0.f, 0.f, 0.f, 0.f); }

// ---------------- merged GEMM + coarse histogram ----------------------------------------
// Blocks [0, gemm_blocks): h = x @ W, 128-node tile, 4x8 thread tile, transposed-x LDS
// (conflict-free a-reads; the round-6 256-tile regressed +12us -- tail quantization at
// 391 blocks + 41KB LDS halving co-residency -- and is reverted to this proven shape).
// Blocks [gemm_blocks..): per-block LDS hist -> global chist (rides in gemm's shadow).
// FMA chain k=0..127 sequential per output => h bitwise identical across rounds.
__global__ __launch_bounds__(256) void k_gemm_hist(const float* __restrict__ x,
                                                   const float* __restrict__ W,
                                                   float* __restrict__ h,
                                                   const int* __restrict__ dst,
                                                   int* __restrict__ chist,
                                                   int n, int E, int gemm_blocks) {
    __shared__ __align__(16) float smem[GKC * 132 + GKC * OUT_DIM_C];  // 24.5 KB union

    if ((int)blockIdx.x < gemm_blocks) {
        float* xs = smem;                 // [k][node], stride 132
        float* Ws = smem + GKC * 132;     // [k][col]
        const int tid = threadIdx.x;
        const int cg = tid & 7;
        const int ng = tid >> 3;
        const int node_base = blockIdx.x * 128;

        float acc[4][8];
        #pragma unroll
        for (int i = 0; i < 4; ++i)
            #pragma unroll
            for (int j = 0; j < 8; ++j) acc[i][j] = 0.f;

        #pragma unroll 1
        for (int c = 0; c < IN_DIM_C / GKC; ++c) {
            __syncthreads();
            #pragma unroll
            for (int i = 0; i < 4; ++i) {
                int idx = tid + i * 256;
                int nd = idx >> 3, k4 = idx & 7;
                int node = node_base + nd;
                float4 v = f4zero();
                if (node < n) v = *(const float4*)&x[(long)node * IN_DIM_C + c * GKC + k4 * 4];
                xs[(k4 * 4 + 0) * 132 + nd] = v.x;
                xs[(k4 * 4 + 1) * 132 + nd] = v.y;
                xs[(k4 * 4 + 2) * 132 + nd] = v.z;
                xs[(k4 * 4 + 3) * 132 + nd] = v.w;
            }
            #pragma unroll
            for (int i = 0; i < 2; ++i) {
                int idx = tid + i * 256;
                ((float4*)Ws)[idx] = ((const float4*)&W[c * GKC * OUT_DIM_C])[idx];
            }
            __syncthreads();

            #pragma unroll
            for (int k = 0; k < GKC; ++k) {
                float4 a = *(const float4*)&xs[k * 132 + ng * 4];
                const float* wr = &Ws[k * OUT_DIM_C + cg * 8];
                float4 b0 = *(const float4*)&wr[0];
                float4 b1 = *(const float4*)&wr[4];
                #pragma unroll
                for (int i = 0; i < 4; ++i) {
                    float av = (i == 0) ? a.x : (i == 1) ? a.y : (i == 2) ? a.z : a.w;
                    acc[i][0] = fmaf(av, b0.x, acc[i][0]);
                    acc[i][1] = fmaf(av, b0.y, acc[i][1]);
                    acc[i][2] = fmaf(av, b0.z, acc[i][2]);
                    acc[i][3] = fmaf(av, b0.w, acc[i][3]);
                    acc[i][4] = fmaf(av, b1.x, acc[i][4]);
                    acc[i][5] = fmaf(av, b1.y, acc[i][5]);
                    acc[i][6] = fmaf(av, b1.z, acc[i][6]);
                    acc[i][7] = fmaf(av, b1.w, acc[i][7]);
                }
            }
        }

        #pragma unroll
        for (int i = 0; i < 4; ++i) {
            int node = node_base + ng * 4 + i;
            if (node < n) {
                *(float4*)&h[(long)node * OUT_DIM_C + cg * 8] =
                    make_float4(acc[i][0], acc[i][1], acc[i][2], acc[i][3]);
                *(float4*)&h[(long)node * OUT_DIM_C + cg * 8 + 4] =
                    make_float4(acc[i][4], acc[i][5], acc[i][6], acc[i][7]);
            }
        }
    } else {
        int* hh = (int*)smem;
        const int tid = threadIdx.x;
        int hb = blockIdx.x - gemm_blocks;
        for (int i = tid; i < KC_MAX; i += 256) hh[i] = 0;
        __syncthreads();
        long base = (long)hb * 4096;
        #pragma unroll
        for (int j = 0; j < 16; ++j) {
            long e = base + j * 256 + tid;
            if (e < E) atomicAdd(&hh[dst[e] >> 8], 1);
        }
        __syncthreads();
        for (int i = tid; i < KC_MAX; i += 256)
            if (hh[i]) atomicAdd(&chist[i], hh[i]);
    }
}

// ---------------- coarse partition (self-contained: scans chist in-block) ----------------
// gcursor is ZERO-initialized; each block computes the global bucket prefix from chist
// (wave-0 dual scan: local hist + global chist) -> no separate k_scanK kernel/bubble.
// packed = (src << 8) | (dst & 255); only 391 concurrent write windows -> L2 combines.
__global__ __launch_bounds__(256) void k_part(const int* __restrict__ src,
                                              const int* __restrict__ dst,
                                              const int* __restrict__ chist,
                                              int* __restrict__ gcursor,
                                              int* __restrict__ part, int E, int kc) {
    __shared__ int hist[KC_MAX];
    __shared__ int offs[KC_MAX];
    __shared__ int cur[KC_MAX];
    __shared__ int gbase[KC_MAX];
    __shared__ int pref[KC_MAX];
    const int tid = threadIdx.x;
    long base = (long)blockIdx.x * PTILE;

    for (int i = tid; i < KC_MAX; i += 256) hist[i] = 0;
    __syncthreads();
    #pragma unroll
    for (int j = 0; j < PTILE / 256; ++j) {
        long e = base + j * 256 + tid;
        if (e < E) atomicAdd(&hist[dst[e] >> 8], 1);
    }
    __syncthreads();
    // wave 0: exclusive scan of local hist AND global chist
    if (tid < 64) {
        int carry = 0, carryG = 0;
        for (int c = 0; c * 64 < kc; ++c) {
            int idx = c * 64 + tid;
            int v  = (idx < kc) ? hist[idx] : 0;
            int vg = (idx < kc) ? chist[idx] : 0;
            int x = v, xg = vg;
            #pragma unroll
            for (int off = 1; off < 64; off <<= 1) {
                int t  = __shfl_up(x, off, 64);
                int tg = __shfl_up(xg, off, 64);
                if (tid >= off) { x += t; xg += tg; }
            }
            if (idx < kc) {
                offs[idx] = carry + x - v;
                cur[idx]  = carry + x - v;
                pref[idx] = carryG + xg - vg;
            }
            carry  += __shfl(x, 63, 64);
            carryG += __shfl(xg, 63, 64);
        }
    }
    __syncthreads();
    for (int b = tid; b < kc; b += 256)
        gbase[b] = hist[b] ? pref[b] + atomicAdd(&gcursor[b], hist[b]) : 0;
    __syncthreads();
    #pragma unroll
    for (int j = 0; j < PTILE / 256; ++j) {
        long e = base + j * 256 + tid;
        if (e < E) {
            int d = dst[e];
            int b = d >> 8;
            int r = atomicAdd(&cur[b], 1);
            part[gbase[b] + r - offs[b]] = (src[e] << 8) | (d & 255);
        }
    }
}

// ---------------- fine sort within bucket (self-contained start/end from chist) ----------
// start(b) = sum chist[0..b-1] via block reduce; also emits CSR offsets, dinv, offsets[n].
__global__ __launch_bounds__(256) void k_sort(const int* __restrict__ part,
                                              const int* __restrict__ chist,
                                              int* __restrict__ part2,
                                              int* __restrict__ offsets,
                                              float* __restrict__ dinv,
                                              int n, int E, int kc) {
    __shared__ int cnt[256];
    __shared__ int cur[256];
    __shared__ int wsum[4], woff[4];
    __shared__ int sred[4];
    __shared__ int sstart;
    const int tid = threadIdx.x;
    const int bkt = blockIdx.x;

    // block reduce: start = sum of chist[i < bkt]
    int s = 0;
    for (int i = tid; i < bkt; i += 256) s += chist[i];
    #pragma unroll
    for (int m = 1; m < 64; m <<= 1) s += __shfl_xor(s, m, 64);
    if ((tid & 63) == 0) sred[tid >> 6] = s;
    cnt[tid] = 0;
    __syncthreads();
    if (tid == 0) sstart = sred[0] + sred[1] + sred[2] + sred[3];
    __syncthreads();
    const int start = sstart;
    const int end = start + chist[bkt];

    for (int i = start + tid; i < end; i += 256)
        atomicAdd(&cnt[part[i] & 255], 1);
    __syncthreads();

    int v = cnt[tid];
    int lane = tid & 63, wv = tid >> 6;
    int x = v;
    #pragma unroll
    for (int off = 1; off < 64; off <<= 1) {
        int t = __shfl_up(x, off, 64);
        if (lane >= off) x += t;
    }
    if (lane == 63) wsum[wv] = x;
    __syncthreads();
    if (tid == 0) { int c = 0; for (int w = 0; w < 4; ++w) { woff[w] = c; c += wsum[w]; } }
    __syncthreads();
    int myloc = woff[wv] + x - v;            // exclusive local offset
    cur[tid] = myloc;
    int node = (bkt << 8) + tid;
    if (node < n) {
        offsets[node] = start + myloc;
        dinv[node] = rsqrtf((float)(v + 1));
    }
    if (bkt == kc - 1 && tid == 0) offsets[n] = E;
    __syncthreads();

    for (int i = start + tid; i < end; i += 256) {
        int p = part[i];
        int r = atomicAdd(&cur[p & 255], 1);
        part2[start + r] = ((unsigned)p) >> 8;   // src node id
    }
}

// ---------------- fused pull+spike: 16 lanes/node, 8-deep gather unroll ------------------
__global__ __launch_bounds__(256) void k_pullspike(const int* __restrict__ offsets,
                                                   const int* __restrict__ part2,
                                                   const float* __restrict__ dinv,
                                                   const float* __restrict__ h,
                                                   const float* __restrict__ b,
                                                   float* __restrict__ o_seq,
                                                   float* __restrict__ z_seq, int n) {
    int gid = blockIdx.x * 256 + threadIdx.x;
    int node = gid >> 4;
    int sub = threadIdx.x & 15;
    if (node >= n) return;
    const float s0 = (sub == 0) ? -1.0f : 1.0f;
    int lane0 = (threadIdx.x & 63) & ~15;

    // ---- pull phase ----
    int o0 = offsets[node], o1 = offsets[node + 1];
    float dd = dinv[node];
    float4 hv = *(const float4*)&h[(long)node * OUT_DIM_C + sub * 4];
    float4 bv = *(const float4*)&b[sub * 4];
    float dd2 = dd * dd;
    float4 g = make_float4(fmaf(dd2, hv.x, bv.x), fmaf(dd2, hv.y, bv.y),
                           fmaf(dd2, hv.z, bv.z), fmaf(dd2, hv.w, bv.w));
    int i = o0;
    for (; i + 8 <= o1; i += 8) {
        int sa0 = part2[i],     sa1 = part2[i + 1], sa2 = part2[i + 2], sa3 = part2[i + 3];
        int sa4 = part2[i + 4], sa5 = part2[i + 5], sa6 = part2[i + 6], sa7 = part2[i + 7];
        float w0 = dinv[sa0] * dd, w1 = dinv[sa1] * dd, w2 = dinv[sa2] * dd, w3 = dinv[sa3] * dd;
        float w4 = dinv[sa4] * dd, w5 = dinv[sa5] * dd, w6 = dinv[sa6] * dd, w7 = dinv[sa7] * dd;
        float4 h0 = *(const float4*)&h[(long)sa0 * OUT_DIM_C + sub * 4];
        float4 h1 = *(const float4*)&h[(long)sa1 * OUT_DIM_C + sub * 4];
        float4 h2 = *(const float4*)&h[(long)sa2 * OUT_DIM_C + sub * 4];
        float4 h3 = *(const float4*)&h[(long)sa3 * OUT_DIM_C + sub * 4];
        float4 h4 = *(const float4*)&h[(long)sa4 * OUT_DIM_C + sub * 4];
        float4 h5 = *(const float4*)&h[(long)sa5 * OUT_DIM_C + sub * 4];
        float4 h6 = *(const float4*)&h[(long)sa6 * OUT_DIM_C + sub * 4];
        float4 h7 = *(const float4*)&h[(long)sa7 * OUT_DIM_C + sub * 4];
        g.x = fmaf(w0, h0.x, g.x); g.y = fmaf(w0, h0.y, g.y);
        g.z = fmaf(w0, h0.z, g.z); g.w = fmaf(w0, h0.w, g.w);
        g.x = fmaf(w1, h1.x, g.x); g.y = fmaf(w1, h1.y, g.y);
        g.z = fmaf(w1, h1.z, g.z); g.w = fmaf(w1, h1.w, g.w);
        g.x = fmaf(w2, h2.x, g.x); g.y = fmaf(w2, h2.y, g.y);
        g.z = fmaf(w2, h2.z, g.z); g.w = fmaf(w2, h2.w, g.w);
        g.x = fmaf(w3, h3.x, g.x); g.y = fmaf(w3, h3.y, g.y);
        g.z = fmaf(w3, h3.z, g.z); g.w = fmaf(w3, h3.w, g.w);
        g.x = fmaf(w4, h4.x, g.x); g.y = fmaf(w4, h4.y, g.y);
        g.z = fmaf(w4, h4.z, g.z); g.w = fmaf(w4, h4.w, g.w);
        g.x = fmaf(w5, h5.x, g.x); g.y = fmaf(w5, h5.y, g.y);
        g.z = fmaf(w5, h5.z, g.z); g.w = fmaf(w5, h5.w, g.w);
        g.x = fmaf(w6, h6.x, g.x); g.y = fmaf(w6, h6.y, g.y);
        g.z = fmaf(w6, h6.z, g.z); g.w = fmaf(w6, h6.w, g.w);
        g.x = fmaf(w7, h7.x, g.x); g.y = fmaf(w7, h7.y, g.y);
        g.z = fmaf(w7, h7.z, g.z); g.w = fmaf(w7, h7.w, g.w);
    }
    for (; i + 4 <= o1; i += 4) {
        int sa0 = part2[i], sa1 = part2[i + 1], sa2 = part2[i + 2], sa3 = part2[i + 3];
        float w0 = dinv[sa0] * dd, w1 = dinv[sa1] * dd;
        float w2 = dinv[sa2] * dd, w3 = dinv[sa3] * dd;
        float4 h0 = *(const float4*)&h[(long)sa0 * OUT_DIM_C + sub * 4];
        float4 h1 = *(const float4*)&h[(long)sa1 * OUT_DIM_C + sub * 4];
        float4 h2 = *(const float4*)&h[(long)sa2 * OUT_DIM_C + sub * 4];
        float4 h3 = *(const float4*)&h[(long)sa3 * OUT_DIM_C + sub * 4];
        g.x = fmaf(w0, h0.x, g.x); g.y = fmaf(w0, h0.y, g.y);
        g.z = fmaf(w0, h0.z, g.z); g.w = fmaf(w0, h0.w, g.w);
        g.x = fmaf(w1, h1.x, g.x); g.y = fmaf(w1, h1.y, g.y);
        g.z = fmaf(w1, h1.z, g.z); g.w = fmaf(w1, h1.w, g.w);
        g.x = fmaf(w2, h2.x, g.x); g.y = fmaf(w2, h2.y, g.y);
        g.z = fmaf(w2, h2.z, g.z); g.w = fmaf(w2, h2.w, g.w);
        g.x = fmaf(w3, h3.x, g.x); g.y = fmaf(w3, h3.y, g.y);
        g.z = fmaf(w3, h3.z, g.z); g.w = fmaf(w3, h3.w, g.w);
    }
    for (; i < o1; ++i) {
        int sidx = part2[i];
        float w = dinv[sidx] * dd;
        float4 h0 = *(const float4*)&h[(long)sidx * OUT_DIM_C + sub * 4];
        g.x = fmaf(w, h0.x, g.x); g.y = fmaf(w, h0.y, g.y);
        g.z = fmaf(w, h0.z, g.z); g.w = fmaf(w, h0.w, g.w);
    }

    // ---- spike phase ----
    float4 origin = f4zero();
    if (sub == 0) origin.x = 1.0f;

    auto step = [&](float4 z, float4& zn, bool& sp) {
        float p = s0 * z.x * g.x + z.y * g.y + z.z * g.z + z.w * g.w;
        p += __shfl_xor(p, 1, 64);
        p += __shfl_xor(p, 2, 64);
        p += __shfl_xor(p, 4, 64);
        p += __shfl_xor(p, 8, 64);
        float4 u = make_float4(fmaf(p, z.x, g.x), fmaf(p, z.y, g.y),
                               fmaf(p, z.z, g.z), fmaf(p, z.w, g.w));
        float q = s0 * u.x * u.x + u.y * u.y + u.z * u.z + u.w * u.w;
        q += __shfl_xor(q, 1, 64);
        q += __shfl_xor(q, 2, 64);
        q += __shfl_xor(q, 4, 64);
        q += __shfl_xor(q, 8, 64);
        float un = sqrtf(fmaxf(q, 1e-7f));
        float c = coshf(un);
        float sh = sinhf(un) / un;
        zn = make_float4(fmaf(c, z.x, sh * u.x), fmaf(c, z.y, sh * u.y),
                         fmaf(c, z.z, sh * u.z), fmaf(c, z.w, sh * u.w));
        float z0 = __shfl(zn.x, lane0, 64);
        float v = acoshf(fmaxf(z0, 1.0f + 1e-7f));
        sp = (v >= 1.0f);
    };

    float4 z1; bool sp0;
    step(origin, z1, sp0);
    float4 r0 = sp0 ? origin : z1;

    float4 z = origin;
    bool at0 = true;
    for (int t = 0; t < T_STEPS; ++t) {
        float4 zn; bool sp;
        if (at0) { sp = sp0; zn = r0; }
        else {
            step(z, zn, sp);
            if (sp) zn = origin;
        }
        *(float4*)&z_seq[(long)t * n * OUT_DIM_C + (long)node * OUT_DIM_C + sub * 4] = zn;
        if (sub == 0) o_seq[(long)t * n + node] = sp ? 1.0f : 0.0f;
        z = zn;
        at0 = sp;
    }
}

// ================= fallback split kernels (used when ws_size too small) ==================
__global__ __launch_bounds__(256) void k_hist(const int* __restrict__ dst,
                                              int* __restrict__ chist, int E) {
    __shared__ int hh[KC_MAX];
    const int tid = threadIdx.x;
    for (int i = tid; i < KC_MAX; i += 256) hh[i] = 0;
    __syncthreads();
    long base = (long)blockIdx.x * 4096;
    #pragma unroll
    for (int j = 0; j < 16; ++j) {
        long e = base + j * 256 + tid;
        if (e < E) atomicAdd(&hh[dst[e] >> 8], 1);
    }
    __syncthreads();
    for (int i = tid; i < KC_MAX; i += 256)
        if (hh[i]) atomicAdd(&chist[i], hh[i]);
}

__global__ __launch_bounds__(256) void k_gemm(const float* __restrict__ x,
                                              const float* __restrict__ W,
                                              float* __restrict__ h, int n) {
    __shared__ __align__(16) float xs[GKC * 132];
    __shared__ __align__(16) float Ws[GKC * OUT_DIM_C];

    const int tid = threadIdx.x;
    const int cg = tid & 7;
    const int ng = tid >> 3;
    const int node_base = blockIdx.x * 128;

    float acc[4][8];
    #pragma unroll
    for (int i = 0; i < 4; ++i)
        #pragma unroll
        for (int j = 0; j < 8; ++j) acc[i][j] = 0.f;

    #pragma unroll 1
    for (int c = 0; c < IN_DIM_C / GKC; ++c) {
        __syncthreads();
        #pragma unroll
        for (int i = 0; i < 4; ++i) {
            int idx = tid + i * 256;
            int nd = idx >> 3, k4 = idx & 7;
            int node = node_base + nd;
            float4 v = f4zero();
            if (node < n) v = *(const float4*)&x[(long)node * IN_DIM_C + c * GKC + k4 * 4];
            xs[(k4 * 4 + 0) * 132 + nd] = v.x;
            xs[(k4 * 4 + 1) * 132 + nd] = v.y;
            xs[(k4 * 4 + 2) * 132 + nd] = v.z;
            xs[(k4 * 4 + 3) * 132 + nd] = v.w;
        }
        #pragma unroll
        for (int i = 0; i < 2; ++i) {
            int idx = tid + i * 256;
            ((float4*)Ws)[idx] = ((const float4*)&W[c * GKC * OUT_DIM_C])[idx];
        }
        __syncthreads();

        #pragma unroll
        for (int k = 0; k < GKC; ++k) {
            float4 a = *(const float4*)&xs[k * 132 + ng * 4];
            const float* wr = &Ws[k * OUT_DIM_C + cg * 8];
            float4 b0 = *(const float4*)&wr[0];
            float4 b1 = *(const float4*)&wr[4];
            #pragma unroll
            for (int i = 0; i < 4; ++i) {
                float av = (i == 0) ? a.x : (i == 1) ? a.y : (i == 2) ? a.z : a.w;
                acc[i][0] = fmaf(av, b0.x, acc[i][0]);
                acc[i][1] = fmaf(av, b0.y, acc[i][1]);
                acc[i][2] = fmaf(av, b0.z, acc[i][2]);
                acc[i][3] = fmaf(av, b0.w, acc[i][3]);
                acc[i][4] = fmaf(av, b1.x, acc[i][4]);
                acc[i][5] = fmaf(av, b1.y, acc[i][5]);
                acc[i][6] = fmaf(av, b1.z, acc[i][6]);
                acc[i][7] = fmaf(av, b1.w, acc[i][7]);
            }
        }
    }

    #pragma unroll
    for (int i = 0; i < 4; ++i) {
        int node = node_base + ng * 4 + i;
        if (node < n) {
            *(float4*)&h[(long)node * OUT_DIM_C + cg * 8] =
                make_float4(acc[i][0], acc[i][1], acc[i][2], acc[i][3]);
            *(float4*)&h[(long)node * OUT_DIM_C + cg * 8 + 4] =
                make_float4(acc[i][4], acc[i][5], acc[i][6], acc[i][7]);
        }
    }
}

__global__ __launch_bounds__(256) void k_pull(const int* __restrict__ offsets,
                                              const int* __restrict__ part2,
                                              const float* __restrict__ dinv,
                                              const float* __restrict__ h,
                                              const float* __restrict__ b,
                                              float* __restrict__ agg, int n) {
    int node = (blockIdx.x * 256 + threadIdx.x) >> 6;
    int lane = threadIdx.x & 63;
    if (node >= n) return;
    int o0 = offsets[node], o1 = offsets[node + 1];
    float dd = dinv[node];
    float acc = fmaf(dd * dd, h[(long)node * OUT_DIM_C + lane], b[lane]);
    int i = o0;
    for (; i + 4 <= o1; i += 4) {
        int s0 = part2[i], s1 = part2[i + 1], s2 = part2[i + 2], s3 = part2[i + 3];
        float n0 = dinv[s0] * dd, n1 = dinv[s1] * dd, n2 = dinv[s2] * dd, n3 = dinv[s3] * dd;
        acc = fmaf(n0, h[(long)s0 * OUT_DIM_C + lane], acc);
        acc = fmaf(n1, h[(long)s1 * OUT_DIM_C + lane], acc);
        acc = fmaf(n2, h[(long)s2 * OUT_DIM_C + lane], acc);
        acc = fmaf(n3, h[(long)s3 * OUT_DIM_C + lane], acc);
    }
    for (; i < o1; ++i) {
        int s = part2[i];
        acc = fmaf(dinv[s] * dd, h[(long)s * OUT_DIM_C + lane], acc);
    }
    agg[(long)node * OUT_DIM_C + lane] = acc;
}

__global__ __launch_bounds__(256) void k_spike(const float* agg,
                                               float* o_seq, float* z_seq, int n) {
    int gid = blockIdx.x * 256 + threadIdx.x;
    int node = gid >> 4;
    int sub = threadIdx.x & 15;
    if (node >= n) return;
    const float s0 = (sub == 0) ? -1.0f : 1.0f;
    int lane0 = (threadIdx.x & 63) & ~15;

    float4 g = *(const float4*)&agg[(long)node * OUT_DIM_C + sub * 4];
    float4 origin = f4zero();
    if (sub == 0) origin.x = 1.0f;

    auto step = [&](float4 z, float4& zn, bool& sp) {
        float p = s0 * z.x * g.x + z.y * g.y + z.z * g.z + z.w * g.w;
        p += __shfl_xor(p, 1, 64);
        p += __shfl_xor(p, 2, 64);
        p += __shfl_xor(p, 4, 64);
        p += __shfl_xor(p, 8, 64);
        float4 u = make_float4(fmaf(p, z.x, g.x), fmaf(p, z.y, g.y),
                               fmaf(p, z.z, g.z), fmaf(p, z.w, g.w));
        float q = s0 * u.x * u.x + u.y * u.y + u.z * u.z + u.w * u.w;
        q += __shfl_xor(q, 1, 64);
        q += __shfl_xor(q, 2, 64);
        q += __shfl_xor(q, 4, 64);
        q += __shfl_xor(q, 8, 64);
        float un = sqrtf(fmaxf(q, 1e-7f));
        float c = coshf(un);
        float sh = sinhf(un) / un;
        zn = make_float4(fmaf(c, z.x, sh * u.x), fmaf(c, z.y, sh * u.y),
                         fmaf(c, z.z, sh * u.z), fmaf(c, z.w, sh * u.w));
        float z0 = __shfl(zn.x, lane0, 64);
        float v = acoshf(fmaxf(z0, 1.0f + 1e-7f));
        sp = (v >= 1.0f);
    };

    float4 z1; bool sp0;
    step(origin, z1, sp0);
    float4 r0 = sp0 ? origin : z1;

    float4 z = origin;
    bool at0 = true;
    for (int t = 0; t < T_STEPS; ++t) {
        float4 zn; bool sp;
        if (at0) { sp = sp0; zn = r0; }
        else {
            step(z, zn, sp);
            if (sp) zn = origin;
        }
        *(float4*)&z_seq[(long)t * n * OUT_DIM_C + (long)node * OUT_DIM_C + sub * 4] = zn;
        if (sub == 0) o_seq[(long)t * n + node] = sp ? 1.0f : 0.0f;
        z = zn;
        at0 = sp;
    }
}

static inline size_t align256(size_t x) { return (x + 255) & ~(size_t)255; }

extern "C" void kernel_launch(void* const* d_in, const int* in_sizes, int n_in,
                              void* d_out, int out_size, void* d_ws, size_t ws_size,
                              hipStream_t stream) {
    const float* x  = (const float*)d_in[0];
    const int*   ei = (const int*)d_in[1];
    const float* W  = (const float*)d_in[2];
    const float* b  = (const float*)d_in[3];
    const int N = in_sizes[0] / IN_DIM_C;   // 100000
    const int E = in_sizes[1] / 2;          // 1600000
    const int KC = (N + 255) >> 8;          // 391 coarse buckets

    float* out   = (float*)d_out;
    float* o_seq = out;                              // [T, N]
    float* z_seq = out + (long)T_STEPS * N;          // [T, N, 64]

    const int* srcp = ei;
    const int* dstp = ei + E;

    // ws layout (fused path): h | part2 | offsets | dinv  (~32.8 MB)
    size_t off_h    = 0;
    size_t off_p2   = align256(off_h + (size_t)N * OUT_DIM_C * 4);
    size_t off_offs = align256(off_p2 + (size_t)E * 4);
    size_t off_dinv = align256(off_offs + (size_t)(N + 1) * 4);
    size_t need     = align256(off_dinv + (size_t)N * 4);

    const int GB = (N + 127) / 128;         // gemm blocks (782)
    const int HB = (E + 4095) / 4096;       // hist blocks (391)

    if (d_ws != nullptr && ws_size >= need) {
        // ---- fused path: pull inputs live in ws, z_seq only written by k_pullspike ----
        float* h       = (float*)((char*)d_ws + off_h);
        int*   part2   = (int*)((char*)d_ws + off_p2);
        int*   offsets = (int*)((char*)d_ws + off_offs);
        float* dinv    = (float*)((char*)d_ws + off_dinv);
        // consumed-before-pullspike scratch aliases z_seq slabs:
        int*   part    = (int*)(z_seq + 0L * N * OUT_DIM_C);      // slab 0: E ints
        int*   chist   = (int*)(z_seq + 1L * N * OUT_DIM_C);      // slab 1: KC ints
        int*   gcursor = chist + KC_MAX;                          // KC ints (zeroed)

        hipMemsetAsync(chist, 0, (size_t)2 * KC_MAX * sizeof(int), stream);
        k_gemm_hist<<<GB + HB, 256, 0, stream>>>(x, W, h, dstp, chist, N, E, GB);
        k_part<<<(E + PTILE - 1) / PTILE, 256, 0, stream>>>(srcp, dstp, chist, gcursor,
                                                            part, E, KC);
        k_sort<<<KC, 256, 0, stream>>>(part, chist, part2, offsets, dinv, N, E, KC);
        k_pullspike<<<(N + 15) / 16, 256, 0, stream>>>(offsets, part2, dinv, h, b,
                                                       o_seq, z_seq, N);
    } else {
        // ---- fallback: split kernels, scratch aliased into z_seq slabs ----
        float* agg     = z_seq;                                   // slab 0
        float* h       = z_seq + 1L * N * OUT_DIM_C;              // slab 1
        int*   part    = (int*)(z_seq + 2L * N * OUT_DIM_C);      // slab 2: E ints
        int*   part2   = (int*)(z_seq + 3L * N * OUT_DIM_C);      // slab 3: E ints
        int*   chist   = (int*)(z_seq + 4L * N * OUT_DIM_C);      // slab 4: KC ints
        int*   gcursor = chist + KC_MAX;
        int*   offsets = gcursor + KC_MAX;
        float* dinv    = (float*)(offsets + N + 1);

        hipMemsetAsync(chist, 0, (size_t)2 * KC_MAX * sizeof(int), stream);
        k_hist<<<HB, 256, 0, stream>>>(dstp, chist, E);
        k_gemm<<<(N + 127) / 128, 256, 0, stream>>>(x, W, h, N);
        k_part<<<(E + PTILE - 1) / PTILE, 256, 0, stream>>>(srcp, dstp, chist, gcursor,
                                                            part, E, KC);
        k_sort<<<KC, 256, 0, stream>>>(part, chist, part2, offsets, dinv, N, E, KC);
        k_pull<<<(N * 64 + 255) / 256, 256, 0, stream>>>(offsets, part2, dinv, h, b, agg, N);
        k_spike<<<(N + 15) / 16, 256, 0, stream>>>(agg, o_seq, z_seq, N);
    }
}